// Round 1
// baseline (152.216 us; speedup 1.0000x reference)
//
#include <hip/hip_runtime.h>
#include <hip/hip_bf16.h>
#include <cmath>

#define B_N 8192
#define D_K 128

typedef short bf16x8 __attribute__((ext_vector_type(8)));
typedef float f32x16 __attribute__((ext_vector_type(16)));

__device__ inline unsigned short f2bf(float f) {
    unsigned u = __builtin_bit_cast(unsigned, f);
    u += 0x7fffu + ((u >> 16) & 1u);   // round-to-nearest-even
    return (unsigned short)(u >> 16);
}

// Convert fp32 Q and A to bf16 in workspace. One thread per 4 elements.
__global__ void cvt_kernel(const float* __restrict__ q, const float* __restrict__ a,
                           unsigned short* __restrict__ qb, unsigned short* __restrict__ ab) {
    int i = blockIdx.x * blockDim.x + threadIdx.x;   // 0 .. B*D/4-1
    float4 vq = reinterpret_cast<const float4*>(q)[i];
    float4 va = reinterpret_cast<const float4*>(a)[i];
    ushort4 oq, oa;
    oq.x = f2bf(vq.x); oq.y = f2bf(vq.y); oq.z = f2bf(vq.z); oq.w = f2bf(vq.w);
    oa.x = f2bf(va.x); oa.y = f2bf(va.y); oa.z = f2bf(va.z); oa.w = f2bf(va.w);
    reinterpret_cast<ushort4*>(qb)[i] = oq;
    reinterpret_cast<ushort4*>(ab)[i] = oa;
}

// Fused sims = Q@A^T + per-row {max, argmax, sum exp, sum w*exp} + final means.
// Block: 512 threads = 8 waves. Block owns 32 rows; wave w owns cols [w*1024, w*1024+1024).
// MFMA 32x32x16 bf16. C/D layout: col = lane&31, row = (reg&3) + 8*(reg>>2) + 4*(lane>>5).
// A-op: lane holds A[m=lane&31][k=(lane>>5)*8 + j], j=0..7 (K=16 per MFMA).
// B-op: lane holds B[k=(lane>>5)*8 + j][n=lane&31]  -> 8 contiguous bf16 from a row of A-matrix.
__launch_bounds__(512, 2)
__global__ void mpl_kernel(const unsigned short* __restrict__ qb,
                           const unsigned short* __restrict__ ab,
                           const int* __restrict__ qids,
                           const float* __restrict__ ranks,
                           float* __restrict__ out) {
    const int tid  = threadIdx.x;
    const int lane = tid & 63;
    const int wave = tid >> 6;          // 0..7
    const int rowBase = blockIdx.x * 32;
    const int half = lane >> 5;         // 0 or 1
    const int l31  = lane & 31;

    // Q fragments for the whole K=128 (8 MFMA k-steps), kept in registers.
    bf16x8 qfrag[8];
    {
        const unsigned short* qrow = qb + (size_t)(rowBase + l31) * D_K + half * 8;
        #pragma unroll
        for (int s = 0; s < 8; ++s)
            qfrag[s] = *reinterpret_cast<const bf16x8*>(qrow + s * 16);
    }

    int qidrow[16];
    #pragma unroll
    for (int r = 0; r < 16; ++r)
        qidrow[r] = qids[rowBase + (r & 3) + 8 * (r >> 2) + 4 * half];

    float den[16], num[16], mxv[16];
    int mxi[16];
    #pragma unroll
    for (int r = 0; r < 16; ++r) { den[r] = 0.f; num[r] = 0.f; mxv[r] = -INFINITY; mxi[r] = 0x7fffffff; }

    const float L2E = 1.4426950408889634f;  // log2(e)
    const float CB  = 64.0f;                // fixed exponent bias; cancels in num/den

    const int colStart = wave * 1024;
    for (int t = 0; t < 32; ++t) {
        const int c  = colStart + t * 32 + l31;
        const int qc = qids[c];
        const float wc = 1.0f - 0.1f * ranks[c];

        const unsigned short* arow = ab + (size_t)c * D_K + half * 8;
        bf16x8 bfrag[8];
        #pragma unroll
        for (int s = 0; s < 8; ++s)
            bfrag[s] = *reinterpret_cast<const bf16x8*>(arow + s * 16);

        f32x16 acc;
        #pragma unroll
        for (int i = 0; i < 16; ++i) acc[i] = 0.f;
        #pragma unroll
        for (int s = 0; s < 8; ++s)
            acc = __builtin_amdgcn_mfma_f32_32x32x16_bf16(qfrag[s], bfrag[s], acc, 0, 0, 0);

        #pragma unroll
        for (int r = 0; r < 16; ++r) {
            float sv = acc[r];
            float e  = exp2f(fmaf(sv, L2E, -CB));   // e^sv * 2^-CB
            den[r] += e;
            float ws = (qc == qidrow[r]) ? wc : 0.0f;
            num[r] = fmaf(ws, e, num[r]);
            bool gt = sv > mxv[r];                  // strict > keeps first occurrence
            mxv[r] = gt ? sv : mxv[r];
            mxi[r] = gt ? c  : mxi[r];
        }
    }

    // Cross-lane merge within each 32-lane half (each half owns the same 16 rows).
    #pragma unroll
    for (int m = 1; m <= 16; m <<= 1) {
        #pragma unroll
        for (int r = 0; r < 16; ++r) {
            float od = __shfl_xor(den[r], m, 64);
            float on = __shfl_xor(num[r], m, 64);
            float ov = __shfl_xor(mxv[r], m, 64);
            int   oi = __shfl_xor(mxi[r], m, 64);
            den[r] += od;
            num[r] += on;
            if (ov > mxv[r] || (ov == mxv[r] && oi < mxi[r])) { mxv[r] = ov; mxi[r] = oi; }
        }
    }

    __shared__ float sden[8][32], snum[8][32], smax[8][32];
    __shared__ int   sidx[8][32];
    if (l31 == 0) {
        #pragma unroll
        for (int r = 0; r < 16; ++r) {
            int lr = (r & 3) + 8 * (r >> 2) + 4 * half;
            sden[wave][lr] = den[r];
            snum[wave][lr] = num[r];
            smax[wave][lr] = mxv[r];
            sidx[wave][lr] = mxi[r];
        }
    }
    __syncthreads();

    if (tid < 32) {
        int lr = tid;
        float d = 0.f, n = 0.f, mv = -INFINITY;
        int mi = 0x7fffffff;
        #pragma unroll
        for (int w = 0; w < 8; ++w) {
            d += sden[w][lr];
            n += snum[w][lr];
            float ov = smax[w][lr]; int oi = sidx[w][lr];
            if (ov > mv || (ov == mv && oi < mi)) { mv = ov; mi = oi; }
        }
        float loss = -logf(n / d + 1e-8f);
        float corr = (qids[mi] == qids[rowBase + lr]) ? 1.0f : 0.0f;
        #pragma unroll
        for (int m = 1; m <= 16; m <<= 1) {
            loss += __shfl_xor(loss, m, 64);
            corr += __shfl_xor(corr, m, 64);
        }
        if (lr == 0) {
            atomicAdd(&out[0], loss * (1.0f / 8192.0f));
            atomicAdd(&out[1], corr * (1.0f / 8192.0f));
        }
    }
}

extern "C" void kernel_launch(void* const* d_in, const int* in_sizes, int n_in,
                              void* d_out, int out_size, void* d_ws, size_t ws_size,
                              hipStream_t stream) {
    const float* q     = (const float*)d_in[0];
    const float* a     = (const float*)d_in[1];
    const int*   qids  = (const int*)d_in[2];
    const float* ranks = (const float*)d_in[3];
    float* out = (float*)d_out;

    unsigned short* qb = (unsigned short*)d_ws;
    unsigned short* ab = qb + (size_t)B_N * D_K;

    hipMemsetAsync(d_out, 0, 2 * sizeof(float), stream);
    cvt_kernel<<<(B_N * D_K / 4) / 256, 256, 0, stream>>>(q, a, qb, ab);
    mpl_kernel<<<B_N / 32, 512, 0, stream>>>(qb, ab, qids, ranks, out);
}